// Round 13
// baseline (84.924 us; speedup 1.0000x reference)
//
#include <hip/hip_runtime.h>

typedef __bf16 bf16x8 __attribute__((ext_vector_type(8)));
typedef float f32x4 __attribute__((ext_vector_type(4)));
typedef float f32x16 __attribute__((ext_vector_type(16)));

#define S_LEN 2048
#define D_DIM 64

// Single-kernel flash attention: 32x32 MFMA swapped-QK^T core with in-register
// softmax + T12 P-conversion; fp32 inputs reg-staged to bf16 LDS in-kernel;
// paired causal chunks (cA, 15-cA) -> uniform 34 KV-tiles per block.
__global__ __launch_bounds__(256, 2) void attn32p(const float* __restrict__ Q,
                                                  const float* __restrict__ K,
                                                  const float* __restrict__ V,
                                                  float* __restrict__ O) {
    const int b    = blockIdx.x;              // 512 = 8 xcd * 32 cu-slot * 2
    const int xcd  = b & 7;
    const int cu   = (b >> 3) & 31;
    const int j    = b >> 8;                  // 0..1
    const int head = xcd * 4 + (cu >> 3);     // 4 heads per XCD
    const int pr   = (cu & 7) + (j << 3);     // 0..15
    const int cA   = pr;                      // first 128-row chunk (nt = 2cA+2)
    const int cB   = 15 - pr;                 // second chunk; total = 34 tiles
    const int nA   = 2 * cA + 2;
    const int NT   = 34;

    const int tid  = threadIdx.x;
    const int wave = tid >> 6;
    const int lane = tid & 63;
    const int l31  = lane & 31;
    const int hi   = lane >> 5;
    const int sw31 = (l31 & 7) << 3;

    const size_t base = (size_t)head * (S_LEN * D_DIM);
    const float qscale = 0.125f * 1.44269504088896340736f;   // D^-0.5 * log2(e)

    __shared__ __align__(16) __bf16 Klds[2][64][64];   // [buf][key][d], col ^ ((key&7)<<3)
    __shared__ __align__(16) __bf16 Vt[2][64][64];     // [buf][d][key], col ^ ((d&7)<<3)

    // staging coords (256 threads cover a 64x64 tile of K and of V)
    const int rk = tid >> 2;            // K row 0..63
    const int ck = (tid & 3) << 4;      // K col 0,16,32,48
    const int kp = tid & 31;            // V key-pair (keys 2kp, 2kp+1)
    const int dc = tid >> 5;            // V d-chunk 0..7
    const int swk = (rk & 7) << 3;

    // ---- Q B-frags (swapped QK^T) for BOTH chunks: col=q=l31, k-dim d=kd*16+hi*8+e ----
    bf16x8 qcur[4], qfB[4];
    {
        const float* qa = Q + base + (size_t)(cA * 128 + wave * 32 + l31) * D_DIM + hi * 8;
        const float* qb = Q + base + (size_t)(cB * 128 + wave * 32 + l31) * D_DIM + hi * 8;
        #pragma unroll
        for (int kd = 0; kd < 4; ++kd) {
            f32x4 a0 = *(const f32x4*)(qa + kd * 16), a1 = *(const f32x4*)(qa + kd * 16 + 4);
            f32x4 b0 = *(const f32x4*)(qb + kd * 16), b1 = *(const f32x4*)(qb + kd * 16 + 4);
            bf16x8 ta, tb;
            #pragma unroll
            for (int e = 0; e < 4; ++e) {
                ta[e] = (__bf16)(a0[e] * qscale); ta[e + 4] = (__bf16)(a1[e] * qscale);
                tb[e] = (__bf16)(b0[e] * qscale); tb[e + 4] = (__bf16)(b1[e] * qscale);
            }
            qcur[kd] = ta; qfB[kd] = tb;
        }
    }

    f32x16 acc0, acc1;                        // O[q=crow(r,hi)][d=l31 (+32 for acc1)]
    #pragma unroll
    for (int r = 0; r < 16; ++r) { acc0[r] = 0.f; acc1[r] = 0.f; }
    float m_r = -1e30f, l_r = 0.f;            // per-lane: q-row = q0w + l31
    int q0w = cA * 128 + wave * 32;

    // staging registers (tile data in flight across the compute phase)
    f32x4 pk[4], pva[2], pvb[2];
    auto loadRegs = [&](int kv0) {
        const float* ks = K + base + (size_t)(kv0 + rk) * D_DIM + ck;
        #pragma unroll
        for (int i = 0; i < 4; ++i) pk[i] = *(const f32x4*)(ks + 4 * i);
        const float* v0 = V + base + (size_t)(kv0 + 2 * kp) * D_DIM + dc * 8;
        pva[0] = *(const f32x4*)v0;           pva[1] = *(const f32x4*)(v0 + 4);
        pvb[0] = *(const f32x4*)(v0 + D_DIM); pvb[1] = *(const f32x4*)(v0 + D_DIM + 4);
    };
    auto writeRegs = [&](int bufi) {
        bf16x8 k0, k1;
        #pragma unroll
        for (int e = 0; e < 4; ++e) {
            k0[e] = (__bf16)pk[0][e]; k0[e + 4] = (__bf16)pk[1][e];
            k1[e] = (__bf16)pk[2][e]; k1[e + 4] = (__bf16)pk[3][e];
        }
        *(bf16x8*)&Klds[bufi][rk][ck ^ swk] = k0;
        *(bf16x8*)&Klds[bufi][rk][(ck + 8) ^ swk] = k1;
        #pragma unroll
        for (int jj = 0; jj < 8; ++jj) {
            const int d = dc * 8 + jj;
            const float av = (jj < 4) ? pva[0][jj & 3] : pva[1][jj & 3];
            const float bv = (jj < 4) ? pvb[0][jj & 3] : pvb[1][jj & 3];
            union { __bf16 h[2]; unsigned int u; } t;
            t.h[0] = (__bf16)av; t.h[1] = (__bf16)bv;
            *(unsigned int*)&Vt[bufi][d][(2 * kp) ^ ((d & 7) << 3)] = t.u;
        }
    };
    auto cvtpk = [](float lo, float hh) {
        unsigned int r;
        asm("v_cvt_pk_bf16_f32 %0, %1, %2" : "=v"(r) : "v"(lo), "v"(hh));
        return r;
    };

    loadRegs(0);
    writeRegs(0);                             // prologue: tile 0 -> buf 0

    for (int t = 0; t < NT; ++t) {
        const int cur = t & 1;
        __syncthreads();                      // buf[cur] staged; prior reads of buf[cur^1] done

        if (t + 1 < NT)                       // issue next tile's loads; hidden under compute
            loadRegs((t + 1 < nA) ? ((t + 1) << 6) : ((t + 1 - nA) << 6));
        const int kv0 = (t < nA) ? (t << 6) : ((t - nA) << 6);

        if (kv0 <= q0w + 31) {                // wave has unmasked work this tile
            // ---- S^T = K Q^T (32x32): lane holds 32 scores of q-row q0w+l31 ----
            f32x16 s0, s1;
            #pragma unroll
            for (int r = 0; r < 16; ++r) { s0[r] = 0.f; s1[r] = 0.f; }
            __builtin_amdgcn_s_setprio(1);
            #pragma unroll
            for (int kd = 0; kd < 4; ++kd) {
                bf16x8 kf0 = *(const bf16x8*)&Klds[cur][l31][(kd * 16 + hi * 8) ^ sw31];
                bf16x8 kf1 = *(const bf16x8*)&Klds[cur][32 + l31][(kd * 16 + hi * 8) ^ sw31];
                s0 = __builtin_amdgcn_mfma_f32_32x32x16_bf16(kf0, qcur[kd], s0, 0, 0, 0);
                s1 = __builtin_amdgcn_mfma_f32_32x32x16_bf16(kf1, qcur[kd], s1, 0, 0, 0);
            }
            __builtin_amdgcn_s_setprio(0);

            // ---- causal mask (diagonal-straddling tiles only) ----
            if (kv0 + 63 > q0w) {
                const int qg = q0w + l31;
                #pragma unroll
                for (int r = 0; r < 16; ++r) {
                    const int cr = (r & 3) + 8 * (r >> 2) + 4 * hi;
                    if (kv0 + cr > qg)      s0[r] = -1e30f;
                    if (kv0 + 32 + cr > qg) s1[r] = -1e30f;
                }
            }

            // ---- in-lane online softmax; tree reductions ----
            float tr[16];
            #pragma unroll
            for (int r = 0; r < 16; ++r) tr[r] = fmaxf(s0[r], s1[r]);
            #pragma unroll
            for (int off = 8; off >= 1; off >>= 1)
                #pragma unroll
                for (int r = 0; r < 16; ++r) if (r < off) tr[r] = fmaxf(tr[r], tr[r + off]);
            float mm = fmaxf(tr[0], __shfl_xor(tr[0], 32));
            if (!__all(mm - m_r <= 8.0f)) {   // defer-max: rescale rarely
                const float mn = fmaxf(m_r, mm);
                const float f = exp2f(m_r - mn);
                m_r = mn;
                l_r *= f;
                #pragma unroll
                for (int r = 0; r < 16; ++r) {
                    const float fr = __shfl(f, (r & 3) + 8 * (r >> 2) + 4 * hi);
                    acc0[r] *= fr; acc1[r] *= fr;
                }
            }
            float u[16];
            #pragma unroll
            for (int r = 0; r < 16; ++r) {
                s0[r] = exp2f(s0[r] - m_r);
                s1[r] = exp2f(s1[r] - m_r);
                u[r] = s0[r] + s1[r];
            }
            #pragma unroll
            for (int off = 8; off >= 1; off >>= 1)
                #pragma unroll
                for (int r = 0; r < 16; ++r) if (r < off) u[r] += u[r + off];
            l_r += u[0] + __shfl_xor(u[0], 32);

            // ---- P -> A-frags in-register (T12: cvt_pk + permlane32_swap), then PV ----
            __builtin_amdgcn_s_setprio(1);
            {   // keys kv0..+31
                unsigned int w01 = cvtpk(s0[0],  s0[1]),  w23 = cvtpk(s0[2],  s0[3]);
                unsigned int w45 = cvtpk(s0[4],  s0[5]),  w67 = cvtpk(s0[6],  s0[7]);
                unsigned int w89 = cvtpk(s0[8],  s0[9]),  wab = cvtpk(s0[10], s0[11]);
                unsigned int wcd = cvtpk(s0[12], s0[13]), wef = cvtpk(s0[14], s0[15]);
                asm("v_permlane32_swap_b32 %0, %1" : "+v"(w01), "+v"(w45));
                asm("v_permlane32_swap_b32 %0, %1" : "+v"(w23), "+v"(w67));
                asm("v_permlane32_swap_b32 %0, %1" : "+v"(w89), "+v"(wcd));
                asm("v_permlane32_swap_b32 %0, %1" : "+v"(wab), "+v"(wef));
                union { unsigned int u[4]; bf16x8 v; } f0 = {{w01, w23, w45, w67}};
                union { unsigned int u[4]; bf16x8 v; } f1 = {{w89, wab, wcd, wef}};
                bf16x8 v00 = *(const bf16x8*)&Vt[cur][l31][(hi * 8) ^ sw31];
                bf16x8 v01 = *(const bf16x8*)&Vt[cur][32 + l31][(hi * 8) ^ sw31];
                acc0 = __builtin_amdgcn_mfma_f32_32x32x16_bf16(f0.v, v00, acc0, 0, 0, 0);
                acc1 = __builtin_amdgcn_mfma_f32_32x32x16_bf16(f0.v, v01, acc1, 0, 0, 0);
                bf16x8 v10 = *(const bf16x8*)&Vt[cur][l31][(16 + hi * 8) ^ sw31];
                bf16x8 v11 = *(const bf16x8*)&Vt[cur][32 + l31][(16 + hi * 8) ^ sw31];
                acc0 = __builtin_amdgcn_mfma_f32_32x32x16_bf16(f1.v, v10, acc0, 0, 0, 0);
                acc1 = __builtin_amdgcn_mfma_f32_32x32x16_bf16(f1.v, v11, acc1, 0, 0, 0);
            }
            {   // keys kv0+32..+63
                unsigned int w01 = cvtpk(s1[0],  s1[1]),  w23 = cvtpk(s1[2],  s1[3]);
                unsigned int w45 = cvtpk(s1[4],  s1[5]),  w67 = cvtpk(s1[6],  s1[7]);
                unsigned int w89 = cvtpk(s1[8],  s1[9]),  wab = cvtpk(s1[10], s1[11]);
                unsigned int wcd = cvtpk(s1[12], s1[13]), wef = cvtpk(s1[14], s1[15]);
                asm("v_permlane32_swap_b32 %0, %1" : "+v"(w01), "+v"(w45));
                asm("v_permlane32_swap_b32 %0, %1" : "+v"(w23), "+v"(w67));
                asm("v_permlane32_swap_b32 %0, %1" : "+v"(w89), "+v"(wcd));
                asm("v_permlane32_swap_b32 %0, %1" : "+v"(wab), "+v"(wef));
                union { unsigned int u[4]; bf16x8 v; } f2 = {{w01, w23, w45, w67}};
                union { unsigned int u[4]; bf16x8 v; } f3 = {{w89, wab, wcd, wef}};
                bf16x8 v20 = *(const bf16x8*)&Vt[cur][l31][(32 + hi * 8) ^ sw31];
                bf16x8 v21 = *(const bf16x8*)&Vt[cur][32 + l31][(32 + hi * 8) ^ sw31];
                acc0 = __builtin_amdgcn_mfma_f32_32x32x16_bf16(f2.v, v20, acc0, 0, 0, 0);
                acc1 = __builtin_amdgcn_mfma_f32_32x32x16_bf16(f2.v, v21, acc1, 0, 0, 0);
                bf16x8 v30 = *(const bf16x8*)&Vt[cur][l31][(48 + hi * 8) ^ sw31];
                bf16x8 v31 = *(const bf16x8*)&Vt[cur][32 + l31][(48 + hi * 8) ^ sw31];
                acc0 = __builtin_amdgcn_mfma_f32_32x32x16_bf16(f3.v, v30, acc0, 0, 0, 0);
                acc1 = __builtin_amdgcn_mfma_f32_32x32x16_bf16(f3.v, v31, acc1, 0, 0, 0);
            }
            __builtin_amdgcn_s_setprio(0);
        }

        if (t + 1 < NT) writeRegs(cur ^ 1);   // cvt + write next tile into idle buffer

        if (t == nA - 1) {                    // ---- seam: finish chunk A, start chunk B ----
            const float inv_own = 1.0f / l_r;
            float* ob = O + base + (size_t)(cA * 128 + wave * 32) * D_DIM + l31;
            #pragma unroll
            for (int r = 0; r < 16; ++r) {
                const int cr = (r & 3) + 8 * (r >> 2) + 4 * hi;
                const float inv = __shfl(inv_own, cr);
                ob[(size_t)cr * D_DIM]      = acc0[r] * inv;
                ob[(size_t)cr * D_DIM + 32] = acc1[r] * inv;
            }
            #pragma unroll
            for (int r = 0; r < 16; ++r) { acc0[r] = 0.f; acc1[r] = 0.f; }
            m_r = -1e30f; l_r = 0.f;
            #pragma unroll
            for (int kd = 0; kd < 4; ++kd) qcur[kd] = qfB[kd];
            q0w = cB * 128 + wave * 32;
        }
    }

    // ---- epilogue: chunk B ----
    const float inv_own = 1.0f / l_r;
    float* ob = O + base + (size_t)(cB * 128 + wave * 32) * D_DIM + l31;
    #pragma unroll
    for (int r = 0; r < 16; ++r) {
        const int cr = (r & 3) + 8 * (r >> 2) + 4 * hi;
        const float inv = __shfl(inv_own, cr);
        ob[(size_t)cr * D_DIM]      = acc0[r] * inv;
        ob[(size_t)cr * D_DIM + 32] = acc1[r] * inv;
    }
}

extern "C" void kernel_launch(void* const* d_in, const int* in_sizes, int n_in,
                              void* d_out, int out_size, void* d_ws, size_t ws_size,
                              hipStream_t stream) {
    const float* q = (const float*)d_in[0];
    const float* k = (const float*)d_in[1];
    const float* v = (const float*)d_in[2];
    float* o = (float*)d_out;
    attn32p<<<dim3(512), dim3(256), 0, stream>>>(q, k, v, o);
}